// Round 1
// baseline (1489.841 us; speedup 1.0000x reference)
//
#include <hip/hip_runtime.h>

// EquivariantLayerBlock: X[512][512][1024] fp32 -> Y[1024][512] fp32, 10 scalar weights.
// Y[c,j] = w0*S2[c] + w1*D[c] + w2*A1[c,j] + w3*A0[c,j] + w4*X[j,j,c]
//        + w5*total + w6*diag_total + w7*R0[j] + w8*R1[j] + w9*Dg[j]

#define N0 1024   // c (e0), contiguous axis of X
#define N1 512    // a,b (e1)

#define TBK 32    // b per chunk (K1)
#define TAK 128   // a per chunk (K1)
#define NBB 16    // b chunks
#define NAB 4     // a chunks
#define NCB 4     // c chunks of 256

// workspace layout (float offsets)
#define OFF_A1  0                                   // A1part[16][512 a][1024 c]
#define OFF_A0  (NBB * N1 * N0)                     // A0part[4][512 b][1024 c]
#define OFF_VEC (OFF_A0 + NAB * N1 * N0)
#define OFF_S2  (OFF_VEC)            // 1024
#define OFF_D   (OFF_VEC + 1024)     // 1024
#define OFF_R0  (OFF_VEC + 2048)     // 512
#define OFF_R1  (OFF_VEC + 2560)     // 512
#define OFF_DG  (OFF_VEC + 3072)     // 512
#define VEC_FLOATS 3584

// ---------------- K1: single streaming pass over X (1 GiB) ----------------
// grid = NCB*NBB*NAB = 256 blocks, 256 threads. Thread <-> one c (coalesced,
// 256B/wave segments). 32 register accumulators = A0 over the a-chunk.
__global__ __launch_bounds__(256) void k1_stream(const float* __restrict__ X,
                                                 float* __restrict__ ws) {
    float* A1part = ws + OFF_A1;
    float* A0part = ws + OFF_A0;
    float* S2 = ws + OFF_S2;
    float* R0 = ws + OFF_R0;
    float* R1 = ws + OFF_R1;

    const int id  = blockIdx.x;
    const int tid = threadIdx.x;
    const int cb = id & 3;
    const int bb = (id >> 2) & 15;
    const int ab = id >> 6;
    const int c  = cb * 256 + tid;
    const int b0 = bb * TBK;
    const int a0 = ab * TAK;

    float acc[TBK];
#pragma unroll
    for (int k = 0; k < TBK; k++) acc[k] = 0.f;

    const float* p = X + ((size_t)a0 * N1 + b0) * N0 + c;
    float* a1out = A1part + ((size_t)bb * N1 + a0) * N0 + c;

    for (int ia = 0; ia < TAK; ia++) {
        float v[TBK];
#pragma unroll
        for (int k = 0; k < TBK; k++) v[k] = p[(size_t)k * N0];
        float s = 0.f;
#pragma unroll
        for (int k = 0; k < TBK; k++) { acc[k] += v[k]; s += v[k]; }
        *a1out = s;  // A1 partial for (bb, a, c)
        // wave-reduce s over 64 c-lanes -> R0[a] (256 atomics/address total)
#pragma unroll
        for (int off = 32; off > 0; off >>= 1) s += __shfl_xor(s, off);
        if ((tid & 63) == 0) atomicAdd(&R0[a0 + ia], s);
        p += (size_t)N1 * N0;
        a1out += N0;
    }

    // S2[c] += sum over this block's (a-chunk, 32 b) — 64 atomics/address
    float tot = 0.f;
#pragma unroll
    for (int k = 0; k < TBK; k++) tot += acc[k];
    atomicAdd(&S2[c], tot);

#pragma unroll
    for (int k = 0; k < TBK; k++) {
        A0part[((size_t)ab * N1 + (b0 + k)) * N0 + c] = acc[k];
        float w = acc[k];
#pragma unroll
        for (int off = 32; off > 0; off >>= 1) w += __shfl_xor(w, off);
        if ((tid & 63) == 0) atomicAdd(&R1[b0 + k], w);  // 64 atomics/address
    }
}

// ---------------- K3: diagonal pass (2 MB) -> D[c], Dg[j] ----------------
// 128 blocks x 256 threads; block handles 4 diagonal rows X[j][j][:].
__global__ __launch_bounds__(256) void k3_diag(const float* __restrict__ X,
                                               float* __restrict__ ws) {
    float* D  = ws + OFF_D;
    float* Dg = ws + OFF_DG;
    const int tid = threadIdx.x;
    const int jbase = blockIdx.x * 4;
    float dacc[4] = {0.f, 0.f, 0.f, 0.f};
    __shared__ float red[256];
    for (int r = 0; r < 4; r++) {
        const int j = jbase + r;
        const float* row = X + (size_t)j * (N1 * N0 + N0);  // X[j][j][0]
        float pr = 0.f;
#pragma unroll
        for (int q = 0; q < 4; q++) {
            float x = row[tid + 256 * q];
            dacc[q] += x;
            pr += x;
        }
        red[tid] = pr;
        __syncthreads();
        for (int s = 128; s; s >>= 1) {
            if (tid < s) red[tid] += red[tid + s];
            __syncthreads();
        }
        if (tid == 0) Dg[j] = red[0];
        __syncthreads();
    }
#pragma unroll
    for (int q = 0; q < 4; q++) atomicAdd(&D[tid + 256 * q], dacc[q]);  // 128/addr
}

// ---------------- K4: reduce chunks + combine + transpose-write Y --------
// 128 blocks (16 c-tiles x 8 j-tiles), 256 threads, 64x64 output tile.
__global__ __launch_bounds__(256) void k4_combine(const float* __restrict__ X,
                                                  const float* __restrict__ W,
                                                  const float* __restrict__ ws,
                                                  float* __restrict__ Y) {
    const float* A1part = ws + OFF_A1;
    const float* A0part = ws + OFF_A0;
    const float* S2 = ws + OFF_S2;
    const float* D  = ws + OFF_D;
    const float* R0 = ws + OFF_R0;
    const float* R1 = ws + OFF_R1;
    const float* Dg = ws + OFF_DG;

    const int tid = threadIdx.x;
    const int ct = blockIdx.x & 15;
    const int jt = blockIdx.x >> 4;
    const int c0 = ct * 64, j0 = jt * 64;

    __shared__ float red[256];
    // scalars: total = sum S2, diag_total = sum D (L2-hot, 8 KB per block)
    float p0 = 0.f, p1 = 0.f;
    for (int i = tid; i < N0; i += 256) { p0 += S2[i]; p1 += D[i]; }
    red[tid] = p0; __syncthreads();
    for (int s = 128; s; s >>= 1) { if (tid < s) red[tid] += red[tid + s]; __syncthreads(); }
    const float total = red[0]; __syncthreads();
    red[tid] = p1; __syncthreads();
    for (int s = 128; s; s >>= 1) { if (tid < s) red[tid] += red[tid + s]; __syncthreads(); }
    const float diag_total = red[0]; __syncthreads();

    const float w0 = W[0], w1 = W[1], w2 = W[2], w3 = W[3], w4 = W[4];
    const float w5 = W[5], w6 = W[6], w7 = W[7], w8 = W[8], w9 = W[9];

    const int cl = tid & 63;   // c lane
    const int jr = tid >> 6;   // j row group
    const int c = c0 + cl;
    const float base_c = w0 * S2[c] + w1 * D[c] + w5 * total + w6 * diag_total;

    __shared__ float T[64][65];
#pragma unroll
    for (int m = 0; m < 16; m++) {
        const int jo = jr * 16 + m;
        const int j = j0 + jo;
        float a1 = 0.f;
#pragma unroll
        for (int t = 0; t < NBB; t++) a1 += A1part[((size_t)t * N1 + j) * N0 + c];
        float a0v = 0.f;
#pragma unroll
        for (int t = 0; t < NAB; t++) a0v += A0part[((size_t)t * N1 + j) * N0 + c];
        const float dgv = X[(size_t)j * (N1 * N0 + N0) + c];  // X[j][j][c]
        const float y = base_c + w2 * a1 + w3 * a0v + w4 * dgv
                      + w7 * R0[j] + w8 * R1[j] + w9 * Dg[j];
        T[jo][cl] = y;
    }
    __syncthreads();
    // write Y[c][j], coalesced over j
#pragma unroll
    for (int m = 0; m < 16; m++) {
        const int crow = jr * 16 + m;
        Y[(size_t)(c0 + crow) * N1 + (j0 + cl)] = T[cl][crow];
    }
}

extern "C" void kernel_launch(void* const* d_in, const int* in_sizes, int n_in,
                              void* d_out, int out_size, void* d_ws, size_t ws_size,
                              hipStream_t stream) {
    const float* X = (const float*)d_in[0];
    const float* W = (const float*)d_in[1];
    float* Y = (float*)d_out;
    float* ws = (float*)d_ws;

    // zero the atomic-accumulated small vectors (S2, D, R0, R1, Dg)
    hipMemsetAsync(ws + OFF_VEC, 0, VEC_FLOATS * sizeof(float), stream);

    k1_stream<<<NCB * NBB * NAB, 256, 0, stream>>>(X, ws);
    k3_diag<<<N1 / 4, 256, 0, stream>>>(X, ws);
    k4_combine<<<16 * 8, 256, 0, stream>>>(X, W, ws, Y);
}

// Round 2
// 1454.742 us; speedup vs baseline: 1.0241x; 1.0241x over previous
//
#include <hip/hip_runtime.h>

// EquivariantLayerBlock: X[512][512][1024] fp32 -> Y[1024][512] fp32, 10 scalar weights.
// Y[c,j] = w0*S2[c] + w1*D[c] + w2*A1[c,j] + w3*A0[c,j] + w4*X[j,j,c]
//        + w5*total + w6*diag_total + w7*R0[j] + w8*R1[j] + w9*Dg[j]
// A1[c,j]=sum_b X[j,b,c], A0[c,j]=sum_a X[a,j,c], S2[c]=sum_{a,b}, D[c]=diag col sum,
// R0[j]=sum_{b,c}X[j,b,c], R1[j]=sum_{a,c}X[a,j,c], Dg[j]=sum_c X[j,j,c].

#define N0 1024   // c, contiguous
#define N1 512    // a, b

#define TBK 32    // b per block (register acc dim)
#define NBB 16    // b chunks
#define NAB 8     // a chunks
#define TAK 64    // a per block (waves split this 4-way)
#define NCB 4     // c quarters (256 floats = 64 float4 per wave)

// ws float offsets
#define OFF_A1P 0u                                   // [16][512][1024] b-chunk partials of A1
#define OFF_A0P (16u*512u*1024u)                     // [8][512][1024]  a-chunk partials of A0
#define OFF_A1S (OFF_A0P + 8u*512u*1024u)            // [512 a][1024 c] = sum_b X[a,b,c]
#define OFF_A0S (OFF_A1S + 512u*1024u)               // [512 b][1024 c] = sum_a X[a,b,c]
#define OFF_S2  (OFF_A0S + 512u*1024u)
#define OFF_D   (OFF_S2 + 1024u)
#define OFF_R0  (OFF_D + 1024u)
#define OFF_R1  (OFF_R0 + 512u)
#define OFF_DG  (OFF_R1 + 512u)

// ---------- K1: barrier-free streaming pass over X (1 GiB) ----------
// grid 512 = cb(4) x bb(16) x ab(8); 256 threads; thread loads float4.
// Wave w handles a = ab*64 + 4*i + w  (no cross-wave traffic in the loop).
__global__ __launch_bounds__(256, 2) void k1_stream(const float4* __restrict__ Xv,
                                                    float* __restrict__ ws) {
    float4* a1p = (float4*)(ws + OFF_A1P);
    float4* a0p = (float4*)(ws + OFF_A0P);

    const int id  = blockIdx.x;
    const int cb = id & 3;
    const int bb = (id >> 2) & 15;
    const int ab = id >> 6;
    const int tid = threadIdx.x;
    const int w = tid >> 6;
    const int l = tid & 63;
    const int c4 = cb * 64 + l;        // float4 index into the 256-f4 row
    const int b0 = bb * TBK;

    float4 acc[TBK];
#pragma unroll
    for (int k = 0; k < TBK; k++) acc[k] = make_float4(0.f, 0.f, 0.f, 0.f);

    const int a0w = ab * TAK + w;
    const float4* p = Xv + ((size_t)(a0w * N1 + b0)) * (N0 / 4) + c4;
    float4* a1o = a1p + ((size_t)bb * N1 + a0w) * (N0 / 4) + c4;

    for (int i = 0; i < TAK / 4; i++) {
        float4 s = make_float4(0.f, 0.f, 0.f, 0.f);
#pragma unroll
        for (int k = 0; k < TBK; k++) {
            float4 v = p[(size_t)k * (N0 / 4)];
            acc[k] += v;
            s += v;
        }
        *a1o = s;                       // A1 partial (bb, a, c): sum over 32 b
        p += (size_t)4 * N1 * (N0 / 4); // a += 4
        a1o += 4 * (N0 / 4);
    }

    // cross-wave reduce acc -> wave 0 -> store A0 partials (once per block)
    __shared__ float4 lred[3][4][64];
    for (int r = 0; r < TBK / 4; r++) {
        if (w > 0) {
#pragma unroll
            for (int q = 0; q < 4; q++) lred[w - 1][q][l] = acc[4 * r + q];
        }
        __syncthreads();
        if (w == 0) {
#pragma unroll
            for (int q = 0; q < 4; q++) {
                float4 t = acc[4 * r + q];
                t += lred[0][q][l];
                t += lred[1][q][l];
                t += lred[2][q][l];
                a0p[((size_t)ab * N1 + (b0 + 4 * r + q)) * (N0 / 4) + c4] = t;
            }
        }
        __syncthreads();
    }
}

// ---------- K2: reduce partial chunks; emit A1sum/A0sum + R0/R1 ----------
// grid 1024: blk<512 -> a-pass (A1), else b-pass (A0). 256 threads = full row.
__global__ __launch_bounds__(256) void k2_reduce(float* __restrict__ ws) {
    const int tid = threadIdx.x;
    __shared__ float red[256];
    if (blockIdx.x < N1) {
        const int a = blockIdx.x;
        const float4* a1p = (const float4*)(ws + OFF_A1P);
        float4 s = make_float4(0.f, 0.f, 0.f, 0.f);
#pragma unroll
        for (int t = 0; t < NBB; t++) s += a1p[((size_t)t * N1 + a) * (N0 / 4) + tid];
        ((float4*)(ws + OFF_A1S))[(size_t)a * (N0 / 4) + tid] = s;
        red[tid] = s.x + s.y + s.z + s.w;
        __syncthreads();
        for (int st = 128; st; st >>= 1) { if (tid < st) red[tid] += red[tid + st]; __syncthreads(); }
        if (tid == 0) ws[OFF_R0 + a] = red[0];
    } else {
        const int b = blockIdx.x - N1;
        const float4* a0p = (const float4*)(ws + OFF_A0P);
        float4 s = make_float4(0.f, 0.f, 0.f, 0.f);
#pragma unroll
        for (int t = 0; t < NAB; t++) s += a0p[((size_t)t * N1 + b) * (N0 / 4) + tid];
        ((float4*)(ws + OFF_A0S))[(size_t)b * (N0 / 4) + tid] = s;
        red[tid] = s.x + s.y + s.z + s.w;
        __syncthreads();
        for (int st = 128; st; st >>= 1) { if (tid < st) red[tid] += red[tid + st]; __syncthreads(); }
        if (tid == 0) ws[OFF_R1 + b] = red[0];
    }
}

// ---------- K3: S2 (from A1sum), D and Dg (diagonal) ----------
__global__ __launch_bounds__(256) void k3_misc(const float* __restrict__ X,
                                               float* __restrict__ ws) {
    const int tid = threadIdx.x;
    const int blk = blockIdx.x;
    if (blk < 4) {                       // S2[c] = sum_a A1sum[a][c]
        const int c = blk * 256 + tid;
        const float* a1s = ws + OFF_A1S;
        float s = 0.f;
        for (int a = 0; a < N1; a++) s += a1s[(size_t)a * N0 + c];
        ws[OFF_S2 + c] = s;
    } else if (blk < 8) {                // D[c] = sum_j X[j,j,c]
        const int c = (blk - 4) * 256 + tid;
        float s = 0.f;
        for (int j = 0; j < N1; j++) s += X[(size_t)j * (N1 * N0 + N0) + c];
        ws[OFF_D + c] = s;
    } else {                             // Dg[j] = sum_c X[j,j,c]
        const int jb = (blk - 8) * 4;
        __shared__ float red[256];
        for (int r = 0; r < 4; r++) {
            const int j = jb + r;
            const float* row = X + (size_t)j * (N1 * N0 + N0);
            float pr = row[tid] + row[tid + 256] + row[tid + 512] + row[tid + 768];
            red[tid] = pr;
            __syncthreads();
            for (int st = 128; st; st >>= 1) { if (tid < st) red[tid] += red[tid + st]; __syncthreads(); }
            if (tid == 0) ws[OFF_DG + j] = red[0];
            __syncthreads();
        }
    }
}

// ---------- K4: combine + transpose-write Y ----------
// 128 blocks (16 c-tiles x 8 j-tiles), 256 threads, 64x64 output tile.
__global__ __launch_bounds__(256) void k4_combine(const float* __restrict__ X,
                                                  const float* __restrict__ W,
                                                  const float* __restrict__ ws,
                                                  float* __restrict__ Y) {
    const float* A1S = ws + OFF_A1S;
    const float* A0S = ws + OFF_A0S;
    const float* S2 = ws + OFF_S2;
    const float* D  = ws + OFF_D;
    const float* R0 = ws + OFF_R0;
    const float* R1 = ws + OFF_R1;
    const float* Dg = ws + OFF_DG;

    const int tid = threadIdx.x;
    const int ct = blockIdx.x & 15;
    const int jt = blockIdx.x >> 4;
    const int c0 = ct * 64, j0 = jt * 64;

    __shared__ float red[256];
    float p0 = 0.f, p1 = 0.f;
    for (int i = tid; i < N0; i += 256) { p0 += S2[i]; p1 += D[i]; }
    red[tid] = p0; __syncthreads();
    for (int s = 128; s; s >>= 1) { if (tid < s) red[tid] += red[tid + s]; __syncthreads(); }
    const float total = red[0]; __syncthreads();
    red[tid] = p1; __syncthreads();
    for (int s = 128; s; s >>= 1) { if (tid < s) red[tid] += red[tid + s]; __syncthreads(); }
    const float diag_total = red[0]; __syncthreads();

    const float w0 = W[0], w1 = W[1], w2 = W[2], w3 = W[3], w4 = W[4];
    const float w5 = W[5], w6 = W[6], w7 = W[7], w8 = W[8], w9 = W[9];

    const int cl = tid & 63;
    const int jr = tid >> 6;
    const int c = c0 + cl;
    const float base_c = w0 * S2[c] + w1 * D[c] + w5 * total + w6 * diag_total;

    __shared__ float T[64][65];
#pragma unroll
    for (int m = 0; m < 16; m++) {
        const int jo = jr * 16 + m;
        const int j = j0 + jo;
        const float a1 = A1S[(size_t)j * N0 + c];
        const float a0v = A0S[(size_t)j * N0 + c];
        const float dgv = X[(size_t)j * (N1 * N0 + N0) + c];
        const float y = base_c + w2 * a1 + w3 * a0v + w4 * dgv
                      + w7 * R0[j] + w8 * R1[j] + w9 * Dg[j];
        T[jo][cl] = y;
    }
    __syncthreads();
#pragma unroll
    for (int m = 0; m < 16; m++) {
        const int crow = jr * 16 + m;
        Y[(size_t)(c0 + crow) * N1 + (j0 + cl)] = T[cl][crow];
    }
}

extern "C" void kernel_launch(void* const* d_in, const int* in_sizes, int n_in,
                              void* d_out, int out_size, void* d_ws, size_t ws_size,
                              hipStream_t stream) {
    const float* X = (const float*)d_in[0];
    const float* W = (const float*)d_in[1];
    float* Y = (float*)d_out;
    float* ws = (float*)d_ws;

    k1_stream<<<NCB * NBB * NAB, 256, 0, stream>>>((const float4*)X, ws);
    k2_reduce<<<2 * N1, 256, 0, stream>>>(ws);
    k3_misc<<<8 + N1 / 4, 256, 0, stream>>>(X, ws);
    k4_combine<<<16 * 8, 256, 0, stream>>>(X, W, ws, Y);
}